// Round 12
// baseline (744.756 us; speedup 1.0000x reference)
//
#include <hip/hip_runtime.h>

// ---------------------------------------------------------------------------
// LowFreqSparseAttention: qkv 1x1conv -> l2norm(q,k) -> S=QK^T*scale ->
// top-k(k=N/2) mask -> softmax -> PV -> proj 1x1conv -> GroupNorm(32 groups).
// B=1, C=256, H=W=64 -> N=4096, 8 heads, hd=32, k_sel=2048.
//
// R12 (post-mortem R11: 668us attn, VALUBusy 59%, MfmaUtil 0. Phase 5 (PV)
// is the largest VALU block: 2048 FMA + 512 cvt + 128 LDS reads per wave.
// Selection path is already minimal and precision-critical -- untouched):
//  * PV via mfma_f32_16x16x32_f16: outT[d][r] = sum_m VT[d][m] * w[m][r].
//    A-frag = VT fp16 tile (lane: row d=lane&15, k=m0+quad*8+j, one global
//    b128); B-frag = weights fp16 from LDS (lane: col r=lane&15, same k;
//    one ds_read_b128 from whf[r&3] -- cols 4..15 produce garbage that only
//    lands in D cols 4..15, which are never read -> NO masking).
//    64 MFMA + 96 loads per wave replace ~4.6K cycles of FMA/cvt.
//  * V produced TRANSPOSED fp16 (VT[h][d][m]) by the QKV-GEMM scatter.
//    fp16 (not bf16): rel err 2^-11 -> output perturbation ~0.002.
//    u8 weights are exact integers in fp16; denominators unchanged.
//  * C/D layout (m89/m91): col=lane&15, row=quad*4+reg -> epilogue partials
//    pv[wv][d][r], cross-wave reduce identical in shape to R11's.
// Selection numerics byte-identical to R11 (absmax expected ~0.03125).
// ---------------------------------------------------------------------------

#define NTOK 4096
#define HD 32
#define NHEADS 8
#define KSEL 2048
#define SCALE 0.17677669529663689f   // 32^-0.5  (folded into l2norm_q)
#define LOG2C 7.73937f               // log2(255 / e^0.1767767)

typedef _Float16 half8v __attribute__((ext_vector_type(8)));
typedef _Float16 half4v __attribute__((ext_vector_type(4)));
typedef float float4v __attribute__((ext_vector_type(4)));

// ---- helpers --------------------------------------------------------------

__device__ __forceinline__ unsigned fkey(float f) {
  unsigned b = __float_as_uint(f);
  return (b & 0x80000000u) ? ~b : (b | 0x80000000u);
}
__device__ __forceinline__ float unfkey(unsigned k) {
  unsigned b = (k & 0x80000000u) ? (k ^ 0x80000000u) : ~k;
  return __uint_as_float(b);
}
// regula-falsi probe in key space, clamped to (klo, khi]
__device__ __forceinline__ unsigned probe_rf(unsigned klo, unsigned khi,
                                             float xlo, float xhi,
                                             int clo, int chi) {
  float t = xlo + (xhi - xlo) * ((float)(clo - KSEL) / (float)(clo - chi));
  unsigned k = fkey(t);
  if (k <= klo) k = klo + 1u;
  if (k > khi) k = khi;
  return k;
}

// ---- kernel 1/4: GEMM  C[M][4096] = A[M][256] * B[256][4096] --------------
// SCATTER: M=768 -> Q [h][n][d] fp32, KT [h][d][n] fp32 (transposed),
//          VT [h][d][n] fp16 (transposed + rounded). else: plain C0.

template <bool SCATTER>
__global__ __launch_bounds__(256) void gemm_k256(
    const float* __restrict__ A, const float* __restrict__ B,
    float* __restrict__ C0, float* __restrict__ C1, float* __restrict__ C2) {
  __shared__ float Wt[64][17];   // +1 pad: avoid 16-way bank conflict
  __shared__ float Xt[16][64];

  const int tid = threadIdx.x;
  const int tx = tid & 15, ty = tid >> 4;
  const int o0 = blockIdx.y * 64, n0 = blockIdx.x * 64;

  const int wr = tid >> 2, wc = (tid & 3) << 2;   // W-tile 64x16 loader
  const int xr = tid >> 4, xc = (tid & 15) << 2;  // X-tile 16x64 loader

  float4 acc[4];
#pragma unroll
  for (int i = 0; i < 4; ++i) acc[i] = make_float4(0.f, 0.f, 0.f, 0.f);

  for (int k0 = 0; k0 < 256; k0 += 16) {
    float4 wv = *(const float4*)(A + (o0 + wr) * 256 + k0 + wc);
    float4 xv = *(const float4*)(B + (k0 + xr) * 4096 + n0 + xc);
    Wt[wr][wc + 0] = wv.x; Wt[wr][wc + 1] = wv.y;
    Wt[wr][wc + 2] = wv.z; Wt[wr][wc + 3] = wv.w;
    *(float4*)&Xt[xr][xc] = xv;
    __syncthreads();
#pragma unroll
    for (int kk = 0; kk < 16; ++kk) {
      float4 b = *(const float4*)&Xt[kk][tx << 2];
#pragma unroll
      for (int i = 0; i < 4; ++i) {
        float a = Wt[(ty << 2) + i][kk];
        acc[i].x += a * b.x; acc[i].y += a * b.y;
        acc[i].z += a * b.z; acc[i].w += a * b.w;
      }
    }
    __syncthreads();
  }

  if (SCATTER) {
#pragma unroll
    for (int i = 0; i < 4; ++i) {
      int o = o0 + (ty << 2) + i;
      int which = o >> 8, rem = o & 255;
      int h = rem >> 5, d = rem & 31;
      int n = n0 + (tx << 2);
      if (which == 1) {
        // KT[h][d][n..n+3] fp32: contiguous float4
        *(float4*)(C1 + h * (HD * NTOK) + d * NTOK + n) = acc[i];
      } else if (which == 2) {
        // VT[h][d][n..n+3] fp16 (RTNE via _Float16 cast): 8B store
        _Float16* vt = (_Float16*)C2;
        half4v hv = {(_Float16)acc[i].x, (_Float16)acc[i].y,
                     (_Float16)acc[i].z, (_Float16)acc[i].w};
        *(half4v*)(vt + h * (HD * NTOK) + d * NTOK + n) = hv;
      } else {
        int base = h * (NTOK * HD) + d;
        C0[base + (n + 0) * HD] = acc[i].x;
        C0[base + (n + 1) * HD] = acc[i].y;
        C0[base + (n + 2) * HD] = acc[i].z;
        C0[base + (n + 3) * HD] = acc[i].w;
      }
    }
  } else {
#pragma unroll
    for (int i = 0; i < 4; ++i) {
      int o = o0 + (ty << 2) + i;
      *(float4*)(C0 + o * 4096 + n0 + (tx << 2)) = acc[i];
    }
  }
}

// ---- kernel 2a: l2norm Q rows [h][n][32], folds SCALE ---------------------

__global__ __launch_bounds__(256) void l2norm_q(float* __restrict__ Q) {
  const int tid = threadIdx.x;
  const int p = blockIdx.x * 8 + (tid >> 5);  // (head*4096+n) row index
  const int d = tid & 31;
  const int idx = p * HD + d;
  float v = Q[idx];
  float ss = v * v;
#pragma unroll
  for (int m = 16; m >= 1; m >>= 1) ss += __shfl_xor(ss, m, 32);
  float nrm = sqrtf(ss);
  Q[idx] = v * SCALE / fmaxf(nrm, 1e-12f);
}

// ---- kernel 2b: l2norm KT columns (norm over d at fixed n) ----------------

__global__ __launch_bounds__(256) void l2norm_kt(float* __restrict__ KT) {
  const int n = blockIdx.x * 256 + threadIdx.x;
  float* P = KT + blockIdx.y * (HD * NTOK) + n;
  float v[HD];
  float ss = 0.f;
#pragma unroll
  for (int d = 0; d < HD; ++d) {
    v[d] = P[d * NTOK];          // coalesced across lanes
    ss += v[d] * v[d];
  }
  float inv = 1.f / fmaxf(sqrtf(ss), 1e-12f);
#pragma unroll
  for (int d = 0; d < HD; ++d) P[d * NTOK] = v[d] * inv;
}

// ---- kernel 3: fused attention (4 rows per block, column-partitioned) -----
// phase2: thread tid owns cols {g*1024 + tid*4 + t}; computes ALL 4 rows.
// phase3: 4-row hybrid selection (regula falsi -> ulp bisection), ==KSEL exit.
// phase4: u8 weight VALUES stored as fp16 (exact) in whf[4][m]; int denoms.
// phase5: PV via mfma_f32_16x16x32_f16, outT[d][r] = sum VT[d][m] w[m][r].

__global__ __launch_bounds__(256) void attn_kernel(
    const float* __restrict__ Q, const float* __restrict__ KT,
    const _Float16* __restrict__ VT, float* __restrict__ AO) {
  __shared__ __align__(16) _Float16 whf[4][NTOK];         // 32 KB, [row][m]
  __shared__ float qs[128];
  __shared__ float pv[4][32][4];                          // 2 KB partials
  __shared__ unsigned ired[2][4][2];                      // bisection dbuf
  __shared__ unsigned dred[4][4];                         // denom partials

  const int tid = threadIdx.x;
  const int wv = tid >> 6, lane = tid & 63;
  const int head = blockIdx.x & 7;          // head == blockIdx%8 -> XCD-pinned
  const int n0 = (blockIdx.x >> 3) << 2;

  const float* Qh = Q + head * (NTOK * HD);
  const float* KTh = KT + head * (HD * NTOK);
  const _Float16* VTh = VT + head * (HD * NTOK);

  // phase 1: stage the block's 4 q rows (already *SCALE from l2norm_q)
  if (tid < 128) qs[tid] = Qh[n0 * HD + tid];
  __syncthreads();

  // phase 2: kr[r][g*4+t] = score(row r, col g*1024 + tid*4 + t).
  // Each K element read by exactly ONE thread. q via b128. FULL unroll
  // keeps kr register-resident (dynamic indexing -> scratch, R4 lesson).
  float kr[4][16];
#pragma unroll
  for (int r = 0; r < 4; ++r)
#pragma unroll
    for (int j = 0; j < 16; ++j) kr[r][j] = 0.f;

  const int cb = tid << 2;
#define GETC(v, i) ((i) == 0 ? (v).x : (i) == 1 ? (v).y : (i) == 2 ? (v).z : (v).w)
#pragma unroll
  for (int dg = 0; dg < 8; ++dg) {
    float4 q40 = *(const float4*)(qs + (dg << 2));
    float4 q41 = *(const float4*)(qs + 32 + (dg << 2));
    float4 q42 = *(const float4*)(qs + 64 + (dg << 2));
    float4 q43 = *(const float4*)(qs + 96 + (dg << 2));
#pragma unroll
    for (int dd = 0; dd < 4; ++dd) {
      const int d = (dg << 2) + dd;
      const float* kp = KTh + d * NTOK + cb;
      float4 kv[4];
#pragma unroll
      for (int g = 0; g < 4; ++g) kv[g] = *(const float4*)(kp + (g << 10));
      const float q0 = GETC(q40, dd), q1 = GETC(q41, dd);
      const float q2 = GETC(q42, dd), q3 = GETC(q43, dd);
#pragma unroll
      for (int g = 0; g < 4; ++g) {
        kr[0][(g << 2) + 0] += q0 * kv[g].x; kr[0][(g << 2) + 1] += q0 * kv[g].y;
        kr[0][(g << 2) + 2] += q0 * kv[g].z; kr[0][(g << 2) + 3] += q0 * kv[g].w;
        kr[1][(g << 2) + 0] += q1 * kv[g].x; kr[1][(g << 2) + 1] += q1 * kv[g].y;
        kr[1][(g << 2) + 2] += q1 * kv[g].z; kr[1][(g << 2) + 3] += q1 * kv[g].w;
        kr[2][(g << 2) + 0] += q2 * kv[g].x; kr[2][(g << 2) + 1] += q2 * kv[g].y;
        kr[2][(g << 2) + 2] += q2 * kv[g].z; kr[2][(g << 2) + 3] += q2 * kv[g].w;
        kr[3][(g << 2) + 0] += q3 * kv[g].x; kr[3][(g << 2) + 1] += q3 * kv[g].y;
        kr[3][(g << 2) + 2] += q3 * kv[g].z; kr[3][(g << 2) + 3] += q3 * kv[g].w;
      }
    }
  }
#undef GETC

  // phase 3: hybrid selection per row (identical to R11).
  unsigned klo0 = 0x417FFFFFu, khi0 = 0xBE800000u;  // fkey(-.25), fkey(.25)
  unsigned klo1 = 0x417FFFFFu, khi1 = 0xBE800000u;
  unsigned klo2 = 0x417FFFFFu, khi2 = 0xBE800000u;
  unsigned klo3 = 0x417FFFFFu, khi3 = 0xBE800000u;
  float xlo0 = -0.25f, xhi0 = 0.25f, xlo1 = -0.25f, xhi1 = 0.25f;
  float xlo2 = -0.25f, xhi2 = 0.25f, xlo3 = -0.25f, xhi3 = 0.25f;
  int clo0 = NTOK, chi0 = 0, clo1 = NTOK, chi1 = 0;
  int clo2 = NTOK, chi2 = 0, clo3 = NTOK, chi3 = 0;
  bool dn0 = false, dn1 = false, dn2 = false, dn3 = false;
  int slot = 0;
#pragma unroll 1
  for (int it = 0; it < 40; ++it) {
    unsigned m0 = dn0 ? klo0
        : ((it < 8 && (khi0 - klo0) > 65536u)
               ? probe_rf(klo0, khi0, xlo0, xhi0, clo0, chi0)
               : klo0 + ((khi0 - klo0 + 1u) >> 1));
    unsigned m1 = dn1 ? klo1
        : ((it < 8 && (khi1 - klo1) > 65536u)
               ? probe_rf(klo1, khi1, xlo1, xhi1, clo1, chi1)
               : klo1 + ((khi1 - klo1 + 1u) >> 1));
    unsigned m2 = dn2 ? klo2
        : ((it < 8 && (khi2 - klo2) > 65536u)
               ? probe_rf(klo2, khi2, xlo2, xhi2, clo2, chi2)
               : klo2 + ((khi2 - klo2 + 1u) >> 1));
    unsigned m3 = dn3 ? klo3
        : ((it < 8 && (khi3 - klo3) > 65536u)
               ? probe_rf(klo3, khi3, xlo3, xhi3, clo3, chi3)
               : klo3 + ((khi3 - klo3 + 1u) >> 1));
    float f0 = unfkey(m0), f1 = unfkey(m1), f2 = unfkey(m2), f3 = unfkey(m3);
    unsigned c0 = 0, c1 = 0, c2 = 0, c3 = 0;
#pragma unroll
    for (int j = 0; j < 16; ++j) {
      c0 += __popcll(__ballot(kr[0][j] >= f0));
      c1 += __popcll(__ballot(kr[1][j] >= f1));
      c2 += __popcll(__ballot(kr[2][j] >= f2));
      c3 += __popcll(__ballot(kr[3][j] >= f3));
    }
    if (lane == 0) {
      ired[slot][wv][0] = c0 | (c1 << 16);
      ired[slot][wv][1] = c2 | (c3 << 16);
    }
    __syncthreads();
    unsigned a01 = ired[slot][0][0] + ired[slot][1][0] +
                   ired[slot][2][0] + ired[slot][3][0];
    unsigned a23 = ired[slot][0][1] + ired[slot][1][1] +
                   ired[slot][2][1] + ired[slot][3][1];
    slot ^= 1;
    int C0 = (int)(a01 & 0xFFFFu), C1 = (int)(a01 >> 16);
    int C2 = (int)(a23 & 0xFFFFu), C3 = (int)(a23 >> 16);
#define BUPD(C, klo, khi, xlo, xhi, clo, chi, dn, mk)                        \
    if (!dn) {                                                               \
      if (C == KSEL) { klo = mk; dn = true; }                                \
      else if (C > KSEL) { klo = mk; xlo = unfkey(mk); clo = C; }            \
      else { khi = mk - 1u; xhi = unfkey(mk); chi = C; }                     \
      if (klo >= khi) dn = true;                                             \
    }
    BUPD(C0, klo0, khi0, xlo0, xhi0, clo0, chi0, dn0, m0)
    BUPD(C1, klo1, khi1, xlo1, xhi1, clo1, chi1, dn1, m1)
    BUPD(C2, klo2, khi2, xlo2, xhi2, clo2, chi2, dn2, m2)
    BUPD(C3, klo3, khi3, xlo3, xhi3, clo3, chi3, dn3, m3)
#undef BUPD
    if (dn0 && dn1 && dn2 && dn3) break;   // uniform across block
  }
  const float tf0 = unfkey(klo0), tf1 = unfkey(klo1);
  const float tf2 = unfkey(klo2), tf3 = unfkey(klo3);

  // phase 4: u8 weight values (exact in fp16) -> whf[row][m]; int denoms.
  // COLUMN MAPPING MATCHES kr: m = g*1024 + tid*4 + t <-> kr[.][(g<<2)+t].
  unsigned id0 = 0, id1 = 0, id2 = 0, id3 = 0;
#pragma unroll
  for (int g = 0; g < 4; ++g) {
    half4v w0v, w1v, w2v, w3v;
#pragma unroll
    for (int t = 0; t < 4; ++t) {
      const int j = (g << 2) + t;
      float s0 = kr[0][j], s1 = kr[1][j], s2 = kr[2][j], s3 = kr[3][j];
      unsigned u0 = (s0 >= tf0) ? (unsigned)rintf(exp2f(__builtin_fmaf(s0, 1.44269504f, LOG2C))) : 0u;
      unsigned u1 = (s1 >= tf1) ? (unsigned)rintf(exp2f(__builtin_fmaf(s1, 1.44269504f, LOG2C))) : 0u;
      unsigned u2 = (s2 >= tf2) ? (unsigned)rintf(exp2f(__builtin_fmaf(s2, 1.44269504f, LOG2C))) : 0u;
      unsigned u3 = (s3 >= tf3) ? (unsigned)rintf(exp2f(__builtin_fmaf(s3, 1.44269504f, LOG2C))) : 0u;
      id0 += u0; id1 += u1; id2 += u2; id3 += u3;
      w0v[t] = (_Float16)(float)u0; w1v[t] = (_Float16)(float)u1;
      w2v[t] = (_Float16)(float)u2; w3v[t] = (_Float16)(float)u3;
    }
    const int mb = (g << 10) + cb;            // 8B-aligned (cb % 4 == 0)
    *(half4v*)&whf[0][mb] = w0v;
    *(half4v*)&whf[1][mb] = w1v;
    *(half4v*)&whf[2][mb] = w2v;
    *(half4v*)&whf[3][mb] = w3v;
  }
  // exact integer denominators: wave-reduce then cross-wave sum
#pragma unroll
  for (int s = 1; s < 64; s <<= 1) {
    id0 += __shfl_xor(id0, s); id1 += __shfl_xor(id1, s);
    id2 += __shfl_xor(id2, s); id3 += __shfl_xor(id3, s);
  }
  if (lane == 0) *(uint4*)&dred[wv][0] = make_uint4(id0, id1, id2, id3);
  __syncthreads();  // whf + dred visible to all
  const float dnm0 = (float)(dred[0][0] + dred[1][0] + dred[2][0] + dred[3][0]);
  const float dnm1 = (float)(dred[0][1] + dred[1][1] + dred[2][1] + dred[3][1]);
  const float dnm2 = (float)(dred[0][2] + dred[1][2] + dred[2][2] + dred[3][2]);
  const float dnm3 = (float)(dred[0][3] + dred[1][3] + dred[2][3] + dred[3][3]);

  // phase 5: PV via MFMA. Wave wv covers m in [wv*1024, +1024): 32 k-steps.
  // D0/D1[i=d(16)][j=r(16)] += A[i][k=m] * B[k][j].
  //  A: lane holds VT[dA = lane&15 (+16 for tile1)][m0 + quad*8 + j], j<8
  //     -> one global b128 per tile per step (VT fp16 [d][m], 16B aligned).
  //  B: lane holds w[m0 + quad*8 + j][rB = lane&15] -> ds_read_b128 from
  //     whf[rB&3]; cols rB>=4 feed only D cols >=4, which are never read.
  const int dA = lane & 15, quad = lane >> 4, rB = lane & 15;
  const _Float16* a0p = VTh + dA * NTOK + (wv << 10) + (quad << 3);
  const _Float16* a1p = a0p + (NTOK << 4);          // d + 16
  const _Float16* bp = &whf[rB & 3][(wv << 10) + (quad << 3)];
  float4v acc0 = {0.f, 0.f, 0.f, 0.f}, acc1 = {0.f, 0.f, 0.f, 0.f};
#pragma unroll
  for (int c = 0; c < 32; ++c) {
    half8v a0 = *(const half8v*)(a0p + (c << 5));
    half8v a1 = *(const half8v*)(a1p + (c << 5));
    half8v b = *(const half8v*)(bp + (c << 5));
    acc0 = __builtin_amdgcn_mfma_f32_16x16x32_f16(a0, b, acc0, 0, 0, 0);
    acc1 = __builtin_amdgcn_mfma_f32_16x16x32_f16(a1, b, acc1, 0, 0, 0);
  }
  // C/D layout: col=lane&15 (=r), row=quad*4+reg (=d within tile).
  if (rB < 4) {
#pragma unroll
    for (int reg = 0; reg < 4; ++reg) {
      pv[wv][(quad << 2) + reg][rB] = acc0[reg];
      pv[wv][16 + (quad << 2) + reg][rB] = acc1[reg];
    }
  }
  __syncthreads();

  if (tid < 128) {
    const int r = tid >> 5, d = tid & 31;
    float val = pv[0][d][r] + pv[1][d][r] + pv[2][d][r] + pv[3][d][r];
    float dn = (r == 0) ? dnm0 : (r == 1) ? dnm1 : (r == 2) ? dnm2 : dnm3;
    val /= dn;
    AO[(head * HD + d) * NTOK + n0 + r] = val;  // [C][N] for proj GEMM
  }
}

// ---- kernel 5: GroupNorm stats (32 groups of 8 ch x 4096 = 32768 vals) ----

__global__ __launch_bounds__(256) void gn_stats(const float* __restrict__ O,
                                                float* __restrict__ ST) {
  const int g = blockIdx.x, tid = threadIdx.x;
  const float4* p4 = (const float4*)(O + g * 32768);
  float s = 0.f, ss = 0.f;
  for (int i = tid; i < 8192; i += 256) {
    float4 v = p4[i];
    s += (v.x + v.y) + (v.z + v.w);
    ss += (v.x * v.x + v.y * v.y) + (v.z * v.z + v.w * v.w);
  }
#pragma unroll
  for (int m = 1; m < 64; m <<= 1) {
    s += __shfl_xor(s, m);
    ss += __shfl_xor(ss, m);
  }
  __shared__ float rs[4], rss[4];
  if ((tid & 63) == 0) { rs[tid >> 6] = s; rss[tid >> 6] = ss; }
  __syncthreads();
  if (tid == 0) {
    float S = rs[0] + rs[1] + rs[2] + rs[3];
    float SS = rss[0] + rss[1] + rss[2] + rss[3];
    float mean = S * (1.f / 32768.f);
    float var = SS * (1.f / 32768.f) - mean * mean;
    ST[g * 2] = mean;
    ST[g * 2 + 1] = rsqrtf(var + 1e-6f);
  }
}

// ---- kernel 6: GroupNorm apply (in place on d_out) ------------------------
// Indexes FLOAT4s: total 1048576/4 = 262144 -> grid 1024 x 256.

__global__ __launch_bounds__(256) void gn_apply(float* __restrict__ O,
                                                const float* __restrict__ ST,
                                                const float* __restrict__ gamma,
                                                const float* __restrict__ beta) {
  const int i4 = blockIdx.x * 256 + threadIdx.x;  // float4 index
  const int c = i4 >> 10, g = c >> 3;
  const float a = ST[g * 2 + 1] * gamma[c];
  const float b = beta[c] - ST[g * 2] * a;
  float4 v = *(float4*)(O + (i4 << 2));
  v.x = v.x * a + b; v.y = v.y * a + b; v.z = v.z * a + b; v.w = v.w * a + b;
  *(float4*)(O + (i4 << 2)) = v;
}

// ---- launch ---------------------------------------------------------------

extern "C" void kernel_launch(void* const* d_in, const int* in_sizes, int n_in,
                              void* d_out, int out_size, void* d_ws,
                              size_t ws_size, hipStream_t stream) {
  const float* x = (const float*)d_in[0];       // [256][4096]
  const float* w_qkv = (const float*)d_in[1];   // [768][256]
  const float* w_proj = (const float*)d_in[2];  // [256][256]
  const float* gamma = (const float*)d_in[3];   // [256]
  const float* beta = (const float*)d_in[4];    // [256]
  float* out = (float*)d_out;                   // [256][4096]

  float* Q = (float*)d_ws;          // [8][4096][32] fp32
  float* KT = Q + 1048576;          // [8][32][4096] fp32 (transposed)
  float* Vs = KT + 1048576;         // [8][32][4096] fp16 (transposed) in
                                    //   the first half of the old V slot
  float* AO = Vs + 1048576;         // [256][4096]
  float* ST = AO + 1048576;         // [32][2]
  _Float16* VT = (_Float16*)Vs;

  gemm_k256<true><<<dim3(64, 12), 256, 0, stream>>>(w_qkv, x, Q, KT, Vs);
  l2norm_q<<<4096, 256, 0, stream>>>(Q);
  l2norm_kt<<<dim3(16, 8), 256, 0, stream>>>(KT);
  attn_kernel<<<8192, 256, 0, stream>>>(Q, KT, VT, AO);
  gemm_k256<false><<<dim3(64, 4), 256, 0, stream>>>(w_proj, AO, out, nullptr, nullptr);
  gn_stats<<<32, 256, 0, stream>>>(out, ST);
  gn_apply<<<1024, 256, 0, stream>>>(out, ST, gamma, beta);
}

// Round 13
// 697.947 us; speedup vs baseline: 1.0671x; 1.0671x over previous
//
#include <hip/hip_runtime.h>

// ---------------------------------------------------------------------------
// LowFreqSparseAttention: qkv 1x1conv -> l2norm(q,k) -> S=QK^T*scale ->
// top-k(k=N/2) mask -> softmax -> PV -> proj 1x1conv -> GroupNorm(32 groups).
// B=1, C=256, H=W=64 -> N=4096, 8 heads, hd=32, k_sel=2048.
//
// R13 = revert to R11 (best measured: 700us total, attn 668us).
// Post-mortem R12: MFMA-PV moved ~120us of VALU issue to the matrix pipe
// (VALUBusy 59->41%, MfmaUtil 2.1%) but duration was unchanged -- the
// kernel is stall-bound, not issue-bound, at its 16 waves/CU occupancy
// cap. That cap is structural: fp32-exact selection requires kr[4][16]
// (64 VGPR) resident per thread -> ~128 VGPR -> 16 waves/CU (m69).
// The fp16-VT variant also regressed the QKV GEMM (+40us). Reverting.
//
// Final structure:
//  * QKV GEMM scatters Q [h][n][d], KT [h][d][n] (transposed), V [h][n][d].
//  * attn: column-partitioned phase 2 (each K byte read by exactly one
//    thread of the block -> K L2 traffic 4.2GB), hybrid regula-falsi +
//    ulp-bisection exact top-k threshold, u8 softmax weights (scale
//    cancels in sum(u*v)/sum(u), integer denominators), scalar PV.
// ---------------------------------------------------------------------------

#define NTOK 4096
#define HD 32
#define NHEADS 8
#define KSEL 2048
#define SCALE 0.17677669529663689f   // 32^-0.5  (folded into l2norm_q)
#define LOG2C 7.73937f               // log2(255 / e^0.1767767)

// ---- helpers --------------------------------------------------------------

__device__ __forceinline__ unsigned fkey(float f) {
  unsigned b = __float_as_uint(f);
  return (b & 0x80000000u) ? ~b : (b | 0x80000000u);
}
__device__ __forceinline__ float unfkey(unsigned k) {
  unsigned b = (k & 0x80000000u) ? (k ^ 0x80000000u) : ~k;
  return __uint_as_float(b);
}
// regula-falsi probe in key space, clamped to (klo, khi]
__device__ __forceinline__ unsigned probe_rf(unsigned klo, unsigned khi,
                                             float xlo, float xhi,
                                             int clo, int chi) {
  float t = xlo + (xhi - xlo) * ((float)(clo - KSEL) / (float)(clo - chi));
  unsigned k = fkey(t);
  if (k <= klo) k = klo + 1u;
  if (k > khi) k = khi;
  return k;
}

// ---- kernel 1/4: GEMM  C[M][4096] = A[M][256] * B[256][4096] --------------
// SCATTER: M=768 -> Q [h][n][d], KT [h][d][n] (transposed!), V [h][n][d].
// else:    M=256 -> plain row-major C0.

template <bool SCATTER>
__global__ __launch_bounds__(256) void gemm_k256(
    const float* __restrict__ A, const float* __restrict__ B,
    float* __restrict__ C0, float* __restrict__ C1, float* __restrict__ C2) {
  __shared__ float Wt[64][17];   // +1 pad: avoid 16-way bank conflict
  __shared__ float Xt[16][64];

  const int tid = threadIdx.x;
  const int tx = tid & 15, ty = tid >> 4;
  const int o0 = blockIdx.y * 64, n0 = blockIdx.x * 64;

  const int wr = tid >> 2, wc = (tid & 3) << 2;   // W-tile 64x16 loader
  const int xr = tid >> 4, xc = (tid & 15) << 2;  // X-tile 16x64 loader

  float4 acc[4];
#pragma unroll
  for (int i = 0; i < 4; ++i) acc[i] = make_float4(0.f, 0.f, 0.f, 0.f);

  for (int k0 = 0; k0 < 256; k0 += 16) {
    float4 wv = *(const float4*)(A + (o0 + wr) * 256 + k0 + wc);
    float4 xv = *(const float4*)(B + (k0 + xr) * 4096 + n0 + xc);
    Wt[wr][wc + 0] = wv.x; Wt[wr][wc + 1] = wv.y;
    Wt[wr][wc + 2] = wv.z; Wt[wr][wc + 3] = wv.w;
    *(float4*)&Xt[xr][xc] = xv;
    __syncthreads();
#pragma unroll
    for (int kk = 0; kk < 16; ++kk) {
      float4 b = *(const float4*)&Xt[kk][tx << 2];
#pragma unroll
      for (int i = 0; i < 4; ++i) {
        float a = Wt[(ty << 2) + i][kk];
        acc[i].x += a * b.x; acc[i].y += a * b.y;
        acc[i].z += a * b.z; acc[i].w += a * b.w;
      }
    }
    __syncthreads();
  }

  if (SCATTER) {
#pragma unroll
    for (int i = 0; i < 4; ++i) {
      int o = o0 + (ty << 2) + i;
      int which = o >> 8, rem = o & 255;
      int h = rem >> 5, d = rem & 31;
      int n = n0 + (tx << 2);
      if (which == 1) {
        // KT[h][d][n..n+3]: contiguous float4
        *(float4*)(C1 + h * (HD * NTOK) + d * NTOK + n) = acc[i];
      } else {
        float* dst = (which == 0) ? C0 : C2;
        int base = h * (NTOK * HD) + d;
        dst[base + (n + 0) * HD] = acc[i].x;
        dst[base + (n + 1) * HD] = acc[i].y;
        dst[base + (n + 2) * HD] = acc[i].z;
        dst[base + (n + 3) * HD] = acc[i].w;
      }
    }
  } else {
#pragma unroll
    for (int i = 0; i < 4; ++i) {
      int o = o0 + (ty << 2) + i;
      *(float4*)(C0 + o * 4096 + n0 + (tx << 2)) = acc[i];
    }
  }
}

// ---- kernel 2a: l2norm Q rows [h][n][32], folds SCALE ---------------------

__global__ __launch_bounds__(256) void l2norm_q(float* __restrict__ Q) {
  const int tid = threadIdx.x;
  const int p = blockIdx.x * 8 + (tid >> 5);  // (head*4096+n) row index
  const int d = tid & 31;
  const int idx = p * HD + d;
  float v = Q[idx];
  float ss = v * v;
#pragma unroll
  for (int m = 16; m >= 1; m >>= 1) ss += __shfl_xor(ss, m, 32);
  float nrm = sqrtf(ss);
  Q[idx] = v * SCALE / fmaxf(nrm, 1e-12f);
}

// ---- kernel 2b: l2norm KT columns (norm over d at fixed n) ----------------

__global__ __launch_bounds__(256) void l2norm_kt(float* __restrict__ KT) {
  const int n = blockIdx.x * 256 + threadIdx.x;
  float* P = KT + blockIdx.y * (HD * NTOK) + n;
  float v[HD];
  float ss = 0.f;
#pragma unroll
  for (int d = 0; d < HD; ++d) {
    v[d] = P[d * NTOK];          // coalesced across lanes
    ss += v[d] * v[d];
  }
  float inv = 1.f / fmaxf(sqrtf(ss), 1e-12f);
#pragma unroll
  for (int d = 0; d < HD; ++d) P[d * NTOK] = v[d] * inv;
}

// ---- kernel 3: fused attention (4 rows per block, column-partitioned) -----
// phase2: thread tid owns cols {g*1024 + tid*4 + t}; computes ALL 4 rows.
//         q via ds_read_b128. kr[4][16] register-resident (full unroll).
// phase3: 4-row hybrid selection: regula falsi on float anchors (while the
//         key bracket is wide), then exact ulp bisection; ==KSEL early exit.
// phase4: u8 weights packed 4 rows/col -> ONE ds_write_b128 per 4 cols;
//         exact integer denominators, block-reduced.
// phase5: PV accumulate u*v (V fp32), cross-lane reduce, write AO[c][n].

__global__ __launch_bounds__(256) void attn_kernel(
    const float* __restrict__ Q, const float* __restrict__ KT,
    const float* __restrict__ V, float* __restrict__ AO) {
  __shared__ __align__(16) unsigned char wtsT[NTOK][4];   // 16 KB, [m][row]
  __shared__ float qs[128];
  __shared__ float pvred[4 * 8 * 4 * 4];                  // 2 KB
  __shared__ unsigned ired[2][4][2];                      // bisection dbuf
  __shared__ unsigned dred[4][4];                         // denom partials

  const int tid = threadIdx.x;
  const int wv = tid >> 6, lane = tid & 63;
  const int head = blockIdx.x & 7;          // head == blockIdx%8 -> XCD-pinned
  const int n0 = (blockIdx.x >> 3) << 2;

  const float* Qh = Q + head * (NTOK * HD);
  const float* KTh = KT + head * (HD * NTOK);
  const float* Vh = V + head * (NTOK * HD);

  // phase 1: stage the block's 4 q rows (already *SCALE from l2norm_q)
  if (tid < 128) qs[tid] = Qh[n0 * HD + tid];
  __syncthreads();

  // phase 2: kr[r][g*4+t] = score(row r, col g*1024 + tid*4 + t).
  // Each K element is read by exactly ONE thread of the block. q read as
  // float4 (b128) per row per 4-d group; component select is compile-time
  // under full unroll. FULL unroll keeps kr register-resident (R4 lesson).
  float kr[4][16];
#pragma unroll
  for (int r = 0; r < 4; ++r)
#pragma unroll
    for (int j = 0; j < 16; ++j) kr[r][j] = 0.f;

  const int cb = tid << 2;
#define GETC(v, i) ((i) == 0 ? (v).x : (i) == 1 ? (v).y : (i) == 2 ? (v).z : (v).w)
#pragma unroll
  for (int dg = 0; dg < 8; ++dg) {
    float4 q40 = *(const float4*)(qs + (dg << 2));
    float4 q41 = *(const float4*)(qs + 32 + (dg << 2));
    float4 q42 = *(const float4*)(qs + 64 + (dg << 2));
    float4 q43 = *(const float4*)(qs + 96 + (dg << 2));
#pragma unroll
    for (int dd = 0; dd < 4; ++dd) {
      const int d = (dg << 2) + dd;
      const float* kp = KTh + d * NTOK + cb;
      float4 kv[4];
#pragma unroll
      for (int g = 0; g < 4; ++g) kv[g] = *(const float4*)(kp + (g << 10));
      const float q0 = GETC(q40, dd), q1 = GETC(q41, dd);
      const float q2 = GETC(q42, dd), q3 = GETC(q43, dd);
#pragma unroll
      for (int g = 0; g < 4; ++g) {
        kr[0][(g << 2) + 0] += q0 * kv[g].x; kr[0][(g << 2) + 1] += q0 * kv[g].y;
        kr[0][(g << 2) + 2] += q0 * kv[g].z; kr[0][(g << 2) + 3] += q0 * kv[g].w;
        kr[1][(g << 2) + 0] += q1 * kv[g].x; kr[1][(g << 2) + 1] += q1 * kv[g].y;
        kr[1][(g << 2) + 2] += q1 * kv[g].z; kr[1][(g << 2) + 3] += q1 * kv[g].w;
        kr[2][(g << 2) + 0] += q2 * kv[g].x; kr[2][(g << 2) + 1] += q2 * kv[g].y;
        kr[2][(g << 2) + 2] += q2 * kv[g].z; kr[2][(g << 2) + 3] += q2 * kv[g].w;
        kr[3][(g << 2) + 0] += q3 * kv[g].x; kr[3][(g << 2) + 1] += q3 * kv[g].y;
        kr[3][(g << 2) + 2] += q3 * kv[g].z; kr[3][(g << 2) + 3] += q3 * kv[g].w;
      }
    }
  }
#undef GETC

  // phase 3: hybrid selection per row. Bracket invariant (key space):
  // count(klo) >= KSEL, answer in [klo, khi]. While the bracket is wide,
  // probe by linear interpolation on the two most recent (value, count)
  // anchors; otherwise ulp midpoint. Exit on count==KSEL (kept set ==
  // reference's top-k set; ties make the count skip KSEL so ==KSEL is
  // tie-free) or klo==khi (exact kth key).
  // |scores| <= 0.1768 < 0.25, so anchors (-0.25 -> 4096, +0.25 -> 0).
  unsigned klo0 = 0x417FFFFFu, khi0 = 0xBE800000u;  // fkey(-.25), fkey(.25)
  unsigned klo1 = 0x417FFFFFu, khi1 = 0xBE800000u;
  unsigned klo2 = 0x417FFFFFu, khi2 = 0xBE800000u;
  unsigned klo3 = 0x417FFFFFu, khi3 = 0xBE800000u;
  float xlo0 = -0.25f, xhi0 = 0.25f, xlo1 = -0.25f, xhi1 = 0.25f;
  float xlo2 = -0.25f, xhi2 = 0.25f, xlo3 = -0.25f, xhi3 = 0.25f;
  int clo0 = NTOK, chi0 = 0, clo1 = NTOK, chi1 = 0;
  int clo2 = NTOK, chi2 = 0, clo3 = NTOK, chi3 = 0;
  bool dn0 = false, dn1 = false, dn2 = false, dn3 = false;
  int slot = 0;
#pragma unroll 1
  for (int it = 0; it < 40; ++it) {
    unsigned m0 = dn0 ? klo0
        : ((it < 8 && (khi0 - klo0) > 65536u)
               ? probe_rf(klo0, khi0, xlo0, xhi0, clo0, chi0)
               : klo0 + ((khi0 - klo0 + 1u) >> 1));
    unsigned m1 = dn1 ? klo1
        : ((it < 8 && (khi1 - klo1) > 65536u)
               ? probe_rf(klo1, khi1, xlo1, xhi1, clo1, chi1)
               : klo1 + ((khi1 - klo1 + 1u) >> 1));
    unsigned m2 = dn2 ? klo2
        : ((it < 8 && (khi2 - klo2) > 65536u)
               ? probe_rf(klo2, khi2, xlo2, xhi2, clo2, chi2)
               : klo2 + ((khi2 - klo2 + 1u) >> 1));
    unsigned m3 = dn3 ? klo3
        : ((it < 8 && (khi3 - klo3) > 65536u)
               ? probe_rf(klo3, khi3, xlo3, xhi3, clo3, chi3)
               : klo3 + ((khi3 - klo3 + 1u) >> 1));
    float f0 = unfkey(m0), f1 = unfkey(m1), f2 = unfkey(m2), f3 = unfkey(m3);
    unsigned c0 = 0, c1 = 0, c2 = 0, c3 = 0;
#pragma unroll
    for (int j = 0; j < 16; ++j) {
      c0 += __popcll(__ballot(kr[0][j] >= f0));
      c1 += __popcll(__ballot(kr[1][j] >= f1));
      c2 += __popcll(__ballot(kr[2][j] >= f2));
      c3 += __popcll(__ballot(kr[3][j] >= f3));
    }
    if (lane == 0) {
      ired[slot][wv][0] = c0 | (c1 << 16);
      ired[slot][wv][1] = c2 | (c3 << 16);
    }
    __syncthreads();
    unsigned a01 = ired[slot][0][0] + ired[slot][1][0] +
                   ired[slot][2][0] + ired[slot][3][0];
    unsigned a23 = ired[slot][0][1] + ired[slot][1][1] +
                   ired[slot][2][1] + ired[slot][3][1];
    slot ^= 1;
    int C0 = (int)(a01 & 0xFFFFu), C1 = (int)(a01 >> 16);
    int C2 = (int)(a23 & 0xFFFFu), C3 = (int)(a23 >> 16);
#define BUPD(C, klo, khi, xlo, xhi, clo, chi, dn, mk)                        \
    if (!dn) {                                                               \
      if (C == KSEL) { klo = mk; dn = true; }                                \
      else if (C > KSEL) { klo = mk; xlo = unfkey(mk); clo = C; }            \
      else { khi = mk - 1u; xhi = unfkey(mk); chi = C; }                     \
      if (klo >= khi) dn = true;                                             \
    }
    BUPD(C0, klo0, khi0, xlo0, xhi0, clo0, chi0, dn0, m0)
    BUPD(C1, klo1, khi1, xlo1, xhi1, clo1, chi1, dn1, m1)
    BUPD(C2, klo2, khi2, xlo2, xhi2, clo2, chi2, dn2, m2)
    BUPD(C3, klo3, khi3, xlo3, xhi3, clo3, chi3, dn3, m3)
#undef BUPD
    if (dn0 && dn1 && dn2 && dn3) break;   // uniform across block
  }
  const float tf0 = unfkey(klo0), tf1 = unfkey(klo1);
  const float tf2 = unfkey(klo2), tf3 = unfkey(klo3);

  // phase 4: u8 weights, 4 rows packed per column, b128 per 4 columns.
  // u = rint(exp(s) * 255/e^smax) in [179,255] kept, 0 masked.
  unsigned id0 = 0, id1 = 0, id2 = 0, id3 = 0;
#pragma unroll
  for (int g = 0; g < 4; ++g) {
    unsigned pk[4];
#pragma unroll
    for (int t = 0; t < 4; ++t) {
      const int j = (g << 2) + t;
      float s0 = kr[0][j], s1 = kr[1][j], s2 = kr[2][j], s3 = kr[3][j];
      unsigned u0 = (s0 >= tf0) ? (unsigned)rintf(exp2f(__builtin_fmaf(s0, 1.44269504f, LOG2C))) : 0u;
      unsigned u1 = (s1 >= tf1) ? (unsigned)rintf(exp2f(__builtin_fmaf(s1, 1.44269504f, LOG2C))) : 0u;
      unsigned u2 = (s2 >= tf2) ? (unsigned)rintf(exp2f(__builtin_fmaf(s2, 1.44269504f, LOG2C))) : 0u;
      unsigned u3 = (s3 >= tf3) ? (unsigned)rintf(exp2f(__builtin_fmaf(s3, 1.44269504f, LOG2C))) : 0u;
      id0 += u0; id1 += u1; id2 += u2; id3 += u3;
      pk[t] = u0 | (u1 << 8) | (u2 << 16) | (u3 << 24);
    }
    const int col = (g << 10) + cb;            // addr = col*4, 16B-aligned
    *(uint4*)&wtsT[col][0] = make_uint4(pk[0], pk[1], pk[2], pk[3]);
  }
  // exact integer denominators: wave-reduce then cross-wave sum
#pragma unroll
  for (int s = 1; s < 64; s <<= 1) {
    id0 += __shfl_xor(id0, s); id1 += __shfl_xor(id1, s);
    id2 += __shfl_xor(id2, s); id3 += __shfl_xor(id3, s);
  }
  if (lane == 0) *(uint4*)&dred[wv][0] = make_uint4(id0, id1, id2, id3);
  __syncthreads();  // wtsT + dred visible to all
  const float dnm0 = (float)(dred[0][0] + dred[1][0] + dred[2][0] + dred[3][0]);
  const float dnm1 = (float)(dred[0][1] + dred[1][1] + dred[2][1] + dred[3][1]);
  const float dnm2 = (float)(dred[0][2] + dred[1][2] + dred[2][2] + dred[3][2]);
  const float dnm3 = (float)(dred[0][3] + dred[1][3] + dred[2][3] + dred[3][3]);

  // phase 5: PV with integer weights. wave wv covers m in [wv*1024, +1024).
  const int slot5 = lane & 7, mg = lane >> 3;
  const int mbase = wv << 10;
  float av[4][4];
#pragma unroll
  for (int r = 0; r < 4; ++r)
#pragma unroll
    for (int c = 0; c < 4; ++c) av[r][c] = 0.f;

#pragma unroll 8
  for (int ii = 0; ii < 128; ++ii) {
    const int m = mbase + (ii << 3) + mg;
    unsigned wq = *(const unsigned*)&wtsT[m][0];   // one b32: rows 0..3
    float4 v = *(const float4*)(Vh + m * HD + (slot5 << 2));
    float w0 = (float)(wq & 0xFFu);          // v_cvt_f32_ubyte0
    float w1 = (float)((wq >> 8) & 0xFFu);   // v_cvt_f32_ubyte1
    float w2 = (float)((wq >> 16) & 0xFFu);  // v_cvt_f32_ubyte2
    float w3 = (float)(wq >> 24);            // v_cvt_f32_ubyte3
    av[0][0] += w0 * v.x; av[0][1] += w0 * v.y; av[0][2] += w0 * v.z; av[0][3] += w0 * v.w;
    av[1][0] += w1 * v.x; av[1][1] += w1 * v.y; av[1][2] += w1 * v.z; av[1][3] += w1 * v.w;
    av[2][0] += w2 * v.x; av[2][1] += w2 * v.y; av[2][2] += w2 * v.z; av[2][3] += w2 * v.w;
    av[3][0] += w3 * v.x; av[3][1] += w3 * v.y; av[3][2] += w3 * v.z; av[3][3] += w3 * v.w;
  }
  // reduce over mg (lane bits 3..5)
#pragma unroll
  for (int r = 0; r < 4; ++r)
#pragma unroll
    for (int c = 0; c < 4; ++c) {
      float x = av[r][c];
      x += __shfl_xor(x, 8); x += __shfl_xor(x, 16); x += __shfl_xor(x, 32);
      av[r][c] = x;
    }
  if (mg == 0) {
#pragma unroll
    for (int r = 0; r < 4; ++r)
#pragma unroll
      for (int c = 0; c < 4; ++c)
        pvred[(((wv << 3) + slot5) * 4 + r) * 4 + c] = av[r][c];
  }
  __syncthreads();

  if (tid < 128) {
    const int r = tid >> 5, d = tid & 31;
    const int sl = d >> 2, c = d & 3;
    float val = 0.f;
#pragma unroll
    for (int w = 0; w < 4; ++w) val += pvred[(((w << 3) + sl) * 4 + r) * 4 + c];
    float dn = (r == 0) ? dnm0 : (r == 1) ? dnm1 : (r == 2) ? dnm2 : dnm3;
    val /= dn;
    AO[(head * HD + d) * NTOK + n0 + r] = val;  // [C][N] for proj GEMM
  }
}

// ---- kernel 5: GroupNorm stats (32 groups of 8 ch x 4096 = 32768 vals) ----

__global__ __launch_bounds__(256) void gn_stats(const float* __restrict__ O,
                                                float* __restrict__ ST) {
  const int g = blockIdx.x, tid = threadIdx.x;
  const float4* p4 = (const float4*)(O + g * 32768);
  float s = 0.f, ss = 0.f;
  for (int i = tid; i < 8192; i += 256) {
    float4 v = p4[i];
    s += (v.x + v.y) + (v.z + v.w);
    ss += (v.x * v.x + v.y * v.y) + (v.z * v.z + v.w * v.w);
  }
#pragma unroll
  for (int m = 1; m < 64; m <<= 1) {
    s += __shfl_xor(s, m);
    ss += __shfl_xor(ss, m);
  }
  __shared__ float rs[4], rss[4];
  if ((tid & 63) == 0) { rs[tid >> 6] = s; rss[tid >> 6] = ss; }
  __syncthreads();
  if (tid == 0) {
    float S = rs[0] + rs[1] + rs[2] + rs[3];
    float SS = rss[0] + rss[1] + rss[2] + rss[3];
    float mean = S * (1.f / 32768.f);
    float var = SS * (1.f / 32768.f) - mean * mean;
    ST[g * 2] = mean;
    ST[g * 2 + 1] = rsqrtf(var + 1e-6f);
  }
}

// ---- kernel 6: GroupNorm apply (in place on d_out) ------------------------
// Indexes FLOAT4s: total 1048576/4 = 262144 -> grid 1024 x 256.

__global__ __launch_bounds__(256) void gn_apply(float* __restrict__ O,
                                                const float* __restrict__ ST,
                                                const float* __restrict__ gamma,
                                                const float* __restrict__ beta) {
  const int i4 = blockIdx.x * 256 + threadIdx.x;  // float4 index
  const int c = i4 >> 10, g = c >> 3;
  const float a = ST[g * 2 + 1] * gamma[c];
  const float b = beta[c] - ST[g * 2] * a;
  float4 v = *(float4*)(O + (i4 << 2));
  v.x = v.x * a + b; v.y = v.y * a + b; v.z = v.z * a + b; v.w = v.w * a + b;
  *(float4*)(O + (i4 << 2)) = v;
}

// ---- launch ---------------------------------------------------------------

extern "C" void kernel_launch(void* const* d_in, const int* in_sizes, int n_in,
                              void* d_out, int out_size, void* d_ws,
                              size_t ws_size, hipStream_t stream) {
  const float* x = (const float*)d_in[0];       // [256][4096]
  const float* w_qkv = (const float*)d_in[1];   // [768][256]
  const float* w_proj = (const float*)d_in[2];  // [256][256]
  const float* gamma = (const float*)d_in[3];   // [256]
  const float* beta = (const float*)d_in[4];    // [256]
  float* out = (float*)d_out;                   // [256][4096]

  float* Q = (float*)d_ws;          // [8][4096][32]
  float* KT = Q + 1048576;          // [8][32][4096]  (transposed)
  float* V = KT + 1048576;          // [8][4096][32]
  float* AO = V + 1048576;          // [256][4096]
  float* ST = AO + 1048576;         // [32][2]

  gemm_k256<true><<<dim3(64, 12), 256, 0, stream>>>(w_qkv, x, Q, KT, V);
  l2norm_q<<<4096, 256, 0, stream>>>(Q);
  l2norm_kt<<<dim3(16, 8), 256, 0, stream>>>(KT);
  attn_kernel<<<8192, 256, 0, stream>>>(Q, KT, V, AO);
  gemm_k256<false><<<dim3(64, 4), 256, 0, stream>>>(w_proj, AO, out, nullptr, nullptr);
  gn_stats<<<32, 256, 0, stream>>>(out, ST);
  gn_apply<<<1024, 256, 0, stream>>>(out, ST, gamma, beta);
}